// Round 4
// baseline (187.388 us; speedup 1.0000x reference)
//
#include <hip/hip_runtime.h>
#include <hip/hip_bf16.h>

#define NV   128

constexpr float EPSV = 1e-5f;
constexpr float TWO_PI_F = 6.28318530717958647692f;
constexpr float DELTA_F  = 0.39269908169872414f;   // f32(2pi/16 in f64)

typedef __attribute__((ext_vector_type(8))) short bfrag8;        // 8 bf16
typedef __attribute__((ext_vector_type(4))) float facc4;         // 4 f32
typedef __attribute__((ext_vector_type(4))) unsigned int uvec4;  // 4 u32

__device__ __forceinline__ unsigned short f2bf(float x) {
    return __bfloat16_as_ushort(__float2bfloat16(x));
}

// ---------------------------------------------------------------------------
// Pre-pack W into bf16 B-fragment order (unchanged from round 3):
// wf[fid*512 + lane*8 + j] = bf16(W[w][g][o]),  fid = (w*5+ot)*3 + s,
//   o = ot*16 + (lane&15),  g = s*32 + (lane>>4)*8 + j  (0 if g >= 80)
// ---------------------------------------------------------------------------
__global__ void pack_w(const float* __restrict__ Wc, unsigned short* __restrict__ wf) {
    int t = blockIdx.x * blockDim.x + threadIdx.x;
    if (t >= 75 * 64) return;
    const int fid = t >> 6, l = t & 63;
    const int s  = fid % 3, wo = fid / 3;
    const int ot = wo % 5,  w  = wo / 5;
    const int o  = ot * 16 + (l & 15);
    const int g0 = s * 32 + (l >> 4) * 8;
    bfrag8 fv;
    #pragma unroll
    for (int j = 0; j < 8; ++j) {
        const int g = g0 + j;
        const float val = (g < 80) ? Wc[(w * 80 + g) * 80 + o] : 0.0f;
        fv[j] = (short)f2bf(val);
    }
    *(bfrag8*)&wf[(size_t)fid * 512 + l * 8] = fv;
}

// ---------------------------------------------------------------------------
// Main kernel: 1 site per block, 4 waves, 2 barriers total.
// Phase A: theta-gaussian TABLE Tg[v][i] (31 consecutive lattice offsets per
//          vertex replace 16x16 exps), K_lds[v] = first wrapping rotation,
//          fa_t[48 rows][128 v] bf16 (row = r*8+c, rows 40-47 & c=6,7 zero).
// Rotations (wave-private, barrier-free): B-frag = u16 gathers from Tg,
//          3 MFMA per K-slice -> C[48][16]; normalize fully in-register
//          (shfl den + v_rcp), write desc_all bf16.
// B3: desc[16k x 96g] @ W[96 x 16o] per (w,otile), max over k, bias, store.
// ---------------------------------------------------------------------------
__global__ __launch_bounds__(256, 3)
void lsres_kernel(const float* __restrict__ feat,
                  const float* __restrict__ rho,
                  const float* __restrict__ theta,
                  const float* __restrict__ mask,
                  const float* __restrict__ mu_rho,
                  const float* __restrict__ mu_theta,
                  const float* __restrict__ sigma_rho,
                  const float* __restrict__ sigma_theta,
                  const float* __restrict__ Wc,
                  const float* __restrict__ bc,
                  const unsigned short* __restrict__ wf,   // may be null
                  float* __restrict__ out)
{
    __shared__ __align__(16) unsigned short fa_t[48 * 128];    // 12 KB, row 256B, XOR-swizzled
    __shared__ __align__(16) unsigned short Tg[128 * 96];      // 24 KB, row 192B, +32B*group stagger
    __shared__ __align__(16) unsigned short desc_all[80 * 104];// 16.25 KB [w*16+k][104]
    __shared__ int K_lds[NV];                                  // 0.5 KB

    const int tid  = threadIdx.x;
    const int lane = tid & 63;
    const int wq   = tid >> 6;
    const int site = blockIdx.x;

    // ---------------- Phase A0: zero pads ----------------
    {
        unsigned int* fz = (unsigned int*)(fa_t + 40 * 128);   // rows 40..47
        for (int i = tid; i < 512; i += 256) fz[i] = 0;
        unsigned int* dz = (unsigned int*)desc_all;            // desc cols 80..95
        for (int i = tid; i < 640; i += 256) {
            const int row = i >> 3, col = i & 7;
            dz[row * 52 + 40 + col] = 0;
        }
    }

    // ---------------- Phase A1: theta table (all 256 threads) ----------------
    {
        const int v = tid >> 1, h = tid & 1;
        const float th = theta[site * NV + v];
        int K = 0;
        #pragma unroll
        for (int k = 0; k < 16; ++k) {
            const float ck = (float)(k * 0.39269908169872414);  // folded constants
            K += (th + ck < TWO_PI_F) ? 1 : 0;                  // same wrap rule as r3
        }
        if (h == 0) K_lds[v] = K;
        const float st0 = sigma_theta[0];
        const float nit = -1.0f / (st0 * st0 + EPSV);
        uvec4 w0, w1;
        #pragma unroll
        for (int p = 0; p < 8; ++p) {
            float e[2];
            #pragma unroll
            for (int z = 0; z < 2; ++z) {
                const int i = h * 16 + p * 2 + z;
                const float nf = (float)(K - 31 + i);
                const float x  = fmaf(nf, DELTA_F, th);
                e[z] = __expf(x * x * nit);
            }
            const unsigned int pk = (unsigned int)f2bf(e[0]) |
                                    ((unsigned int)f2bf(e[1]) << 16);
            if (p < 4) w0[p] = pk; else w1[p - 4] = pk;
        }
        char* rowp = (char*)Tg + v * 192 + ((v >> 3) & 3) * 32 + h * 32;
        *(uvec4*)rowp        = w0;
        *(uvec4*)(rowp + 16) = w1;
    }

    // ---------------- Phase A2: rho gaussians * mask * feat ----------------
    if (tid < NV) {
        const int v = tid;
        const float rv = rho[site * NV + v];
        const float mv = mask[site * NV + v];
        float f[6];
        #pragma unroll
        for (int c = 0; c < 5; ++c) f[c] = feat[(site * NV + v) * 5 + c];
        f[5] = 1.0f;
        #pragma unroll
        for (int r = 0; r < 5; ++r) {
            const float mr  = mu_rho[r * 16];
            const float sr  = sigma_rho[r * 16];
            const float inv = 1.0f / (sr * sr + EPSV);
            const float d   = rv - mr;
            const float rg  = __expf(-d * d * inv) * mv;
            #pragma unroll
            for (int c = 0; c < 6; ++c) {
                const int cr = r * 8 + c;
                const int byte = cr * 256 + ((v * 2) ^ ((cr & 7) << 4));
                fa_t[byte >> 1] = f2bf(rg * f[c]);
            }
        }
        // rows r*8+6, r*8+7 are never read (C rows c=6,7 unused); rows 40-47 zeroed
    }
    __syncthreads();

    // ---------------- per-wave setup ----------------
    const int q = lane >> 4, t = lane & 15;

    bfrag8 afrag[3][4];
    #pragma unroll
    for (int m = 0; m < 3; ++m)
        #pragma unroll
        for (int s = 0; s < 4; ++s) {
            const int cr = m * 16 + t;
            const int byte = cr * 256 + ((s * 64 + q * 16) ^ ((cr & 7) << 4));
            afrag[m][s] = *(const bfrag8*)((const char*)fa_t + byte);
        }

    // per-slot gather bases: addr(k) = Ac - 32*[k >= Kv] + 2*(k - 4*wq)
    int Kv[4][8], Ac[4][8];
    const int lc = q * 1536 + q * 32 + 2 * (31 - t) + 8 * wq;
    #pragma unroll
    for (int s = 0; s < 4; ++s) {
        const int4 ka = *(const int4*)&K_lds[s * 32 + q * 8];
        const int4 kb = *(const int4*)&K_lds[s * 32 + q * 8 + 4];
        Kv[s][0] = ka.x; Kv[s][1] = ka.y; Kv[s][2] = ka.z; Kv[s][3] = ka.w;
        Kv[s][4] = kb.x; Kv[s][5] = kb.y; Kv[s][6] = kb.z; Kv[s][7] = kb.w;
        #pragma unroll
        for (int j = 0; j < 8; ++j)
            Ac[s][j] = lc + s * 6144 + j * 192 - 2 * Kv[s][j];
    }

    // ---------------- rotation loop (barrier-free) ----------------
    #pragma unroll
    for (int i = 0; i < 4; ++i) {
        const int k = wq * 4 + i;
        facc4 acc[3];
        #pragma unroll
        for (int m = 0; m < 3; ++m) acc[m] = (facc4){0.f, 0.f, 0.f, 0.f};

        #pragma unroll
        for (int s = 0; s < 4; ++s) {
            uvec4 bu;
            #pragma unroll
            for (int jp = 0; jp < 4; ++jp) {
                int a0 = Ac[s][2 * jp];
                int a1 = Ac[s][2 * jp + 1];
                if (k >= Kv[s][2 * jp])     a0 -= 32;
                if (k >= Kv[s][2 * jp + 1]) a1 -= 32;
                const unsigned int e0 = *(const unsigned short*)((const char*)Tg + a0 + 2 * i);
                const unsigned int e1 = *(const unsigned short*)((const char*)Tg + a1 + 2 * i);
                bu[jp] = e0 | (e1 << 16);
            }
            const bfrag8 b = __builtin_bit_cast(bfrag8, bu);
            acc[0] = __builtin_amdgcn_mfma_f32_16x16x32_bf16(afrag[0][s], b, acc[0], 0, 0, 0);
            acc[1] = __builtin_amdgcn_mfma_f32_16x16x32_bf16(afrag[1][s], b, acc[1], 0, 0, 0);
            acc[2] = __builtin_amdgcn_mfma_f32_16x16x32_bf16(afrag[2][s], b, acc[2], 0, 0, 0);
        }

        // in-register normalize -> desc_all (bf16)
        const int cbase = (q & 1) * 4;
        #pragma unroll
        for (int m = 0; m < 3; ++m) {
            const float den = __shfl(acc[m][1], ((q | 1) << 4) | t, 64);
            const float rcp = __builtin_amdgcn_rcpf(den + EPSV);
            const int r = 2 * m + (q >> 1);
            if (r < 5) {
                #pragma unroll
                for (int jj = 0; jj < 4; ++jj) {
                    const int c = cbase + jj;                 // = w when < 5
                    if (c < 5) {
                        const float val = acc[m][jj] * rcp;
                        desc_all[(c * 16 + k) * 104 + r * 16 + t] = f2bf(val);
                    }
                }
            }
        }
    }
    __syncthreads();

    // ---------------- B3: cf[k][o] = desc[w] @ W[w], max over k ----------------
    for (int u = wq; u < 25; u += 4) {
        const int w  = u / 5;
        const int ot = u - w * 5;
        const int o  = ot * 16 + (lane & 15);
        facc4 acc = {0.f, 0.f, 0.f, 0.f};
        #pragma unroll
        for (int s = 0; s < 3; ++s) {
            const bfrag8 a = *(const bfrag8*)
                &desc_all[(w * 16 + (lane & 15)) * 104 + s * 32 + (lane >> 4) * 8];
            bfrag8 bf;
            if (wf) {
                bf = *(const bfrag8*)&wf[((size_t)((w * 5 + ot) * 3 + s)) * 512 + lane * 8];
            } else {
                #pragma unroll
                for (int j = 0; j < 8; ++j) {
                    const int g = s * 32 + (lane >> 4) * 8 + j;
                    const float val = (g < 80) ? Wc[(w * 80 + g) * 80 + o] : 0.0f;
                    bf[j] = (short)f2bf(val);
                }
            }
            acc = __builtin_amdgcn_mfma_f32_16x16x32_bf16(a, bf, acc, 0, 0, 0);
        }
        float mx = fmaxf(fmaxf(acc[0], acc[1]), fmaxf(acc[2], acc[3]));
        mx = fmaxf(mx, __shfl_xor(mx, 16, 64));
        mx = fmaxf(mx, __shfl_xor(mx, 32, 64));
        if (lane < 16) {
            out[(size_t)site * 400 + w * 80 + o] = mx + bc[w * 80 + o];
        }
    }
}

extern "C" void kernel_launch(void* const* d_in, const int* in_sizes, int n_in,
                              void* d_out, int out_size, void* d_ws, size_t ws_size,
                              hipStream_t stream) {
    const float* feat        = (const float*)d_in[0];
    const float* rho         = (const float*)d_in[1];
    const float* theta       = (const float*)d_in[2];
    const float* mask        = (const float*)d_in[3];
    const float* mu_rho      = (const float*)d_in[4];
    const float* mu_theta    = (const float*)d_in[5];
    const float* sigma_rho   = (const float*)d_in[6];
    const float* sigma_theta = (const float*)d_in[7];
    const float* Wc          = (const float*)d_in[8];
    const float* bc          = (const float*)d_in[9];
    float* outp              = (float*)d_out;

    unsigned short* wfp = nullptr;
    if (ws_size >= (size_t)75 * 512 * sizeof(unsigned short)) {
        wfp = (unsigned short*)d_ws;
        pack_w<<<19, 256, 0, stream>>>(Wc, wfp);
    }

    const int sites = in_sizes[1] / NV;   // B*S = 4096
    lsres_kernel<<<sites, 256, 0, stream>>>(feat, rho, theta, mask,
                                            mu_rho, mu_theta, sigma_rho, sigma_theta,
                                            Wc, bc, wfp, outp);
}

// Round 9
// 135.921 us; speedup vs baseline: 1.3787x; 1.3787x over previous
//
#include <hip/hip_runtime.h>
#include <hip/hip_bf16.h>

#define NV   128

constexpr float EPSV = 1e-5f;
constexpr float TWO_PI_F = 6.28318530717958647692f;
constexpr float DELTA_F  = 0.39269908169872414f;   // f32(2pi/16 in f64)

typedef __attribute__((ext_vector_type(8))) short bfrag8;        // 8 bf16
typedef __attribute__((ext_vector_type(4))) float facc4;         // 4 f32
typedef __attribute__((ext_vector_type(4))) unsigned int uvec4;  // 4 u32

__device__ __forceinline__ unsigned short f2bf(float x) {
    return __bfloat16_as_ushort(__float2bfloat16(x));
}

// ---------------------------------------------------------------------------
// Pre-pack W into bf16 B-fragment order (unchanged, passed rounds 3/4):
// wf[fid*512 + lane*8 + j] = bf16(W[w][g][o]),  fid = (w*5+ot)*3 + s,
//   o = ot*16 + (lane&15),  g = s*32 + (lane>>4)*8 + j  (0 if g >= 80)
// ---------------------------------------------------------------------------
__global__ void pack_w(const float* __restrict__ Wc, unsigned short* __restrict__ wf) {
    int t = blockIdx.x * blockDim.x + threadIdx.x;
    if (t >= 75 * 64) return;
    const int fid = t >> 6, l = t & 63;
    const int s  = fid % 3, wo = fid / 3;
    const int ot = wo % 5,  w  = wo / 5;
    const int o  = ot * 16 + (l & 15);
    const int g0 = s * 32 + (l >> 4) * 8;
    bfrag8 fv;
    #pragma unroll
    for (int j = 0; j < 8; ++j) {
        const int g = g0 + j;
        const float val = (g < 80) ? Wc[(w * 80 + g) * 80 + o] : 0.0f;
        fv[j] = (short)f2bf(val);
    }
    *(bfrag8*)&wf[(size_t)fid * 512 + l * 8] = fv;
}

// ---------------------------------------------------------------------------
// Main kernel: 1 site per block, 4 waves, 2 barriers.
// Phase A1: REVERSED theta table Trev[v][j] = exp(-(theta+(K-j)*D)^2/s^2),
//           96-byte row pitch + ((v>>3)&1)*32 stagger (rows provably
//           disjoint: 32 + 64 <= 96 — r6's overlap bug fixed).
//           Element for (v,t,k): j = t + off, off = ((K-k-1)&15)+1.
// Rotations (wave-private, barrier-free): per element 4 indep VALU + 1
//           ds_read_u16; 3 MFMA per 32-K slice; in-register normalize.
// fa_t: 40 rows only; afrag[2] zeroed in-reg for t>=8 (MFMA rows indep).
// B3: desc[16k x 96g] @ W[96 x 16o] per (w,otile), max over k, bias, store.
// LDS 38.4 KB -> 4 blocks/CU.
// ---------------------------------------------------------------------------
__global__ __launch_bounds__(256, 4)
void lsres_kernel(const float* __restrict__ feat,
                  const float* __restrict__ rho,
                  const float* __restrict__ theta,
                  const float* __restrict__ mask,
                  const float* __restrict__ mu_rho,
                  const float* __restrict__ mu_theta,
                  const float* __restrict__ sigma_rho,
                  const float* __restrict__ sigma_theta,
                  const float* __restrict__ Wc,
                  const float* __restrict__ bc,
                  const unsigned short* __restrict__ wf,   // may be null
                  float* __restrict__ out)
{
    __shared__ __align__(16) unsigned short fa_t[40 * 128];     // 10 KB, XOR-swizzled
    __shared__ __align__(16) unsigned short Trev[6144];         // 12 KB, 96B pitch
    __shared__ __align__(16) unsigned short desc_all[80 * 104]; // 16.25 KB
    __shared__ unsigned char K_pack[NV];                        // 128 B

    const int tid  = threadIdx.x;
    const int lane = tid & 63;
    const int wq   = tid >> 6;
    const int site = blockIdx.x;

    // ---------------- Phase A0: zero desc pad cols (g=80..95) ----------------
    {
        unsigned int* dz = (unsigned int*)desc_all;
        for (int i = tid; i < 640; i += 256) {
            const int row = i >> 3, col = i & 7;
            dz[row * 52 + 40 + col] = 0;
        }
    }

    // ---------------- Phase A1: reversed theta table ----------------
    {
        const int v = tid >> 1, h = tid & 1;
        const float th = theta[site * NV + v];
        int K = 0;
        #pragma unroll
        for (int k = 0; k < 16; ++k) {
            const float ck = (float)(k * 0.39269908169872414);  // same wrap rule as r3/r4
            K += (th + ck < TWO_PI_F) ? 1 : 0;
        }
        if (h == 0) K_pack[v] = (unsigned char)K;
        const float st0 = sigma_theta[0];
        const float nit = -1.0f / (st0 * st0 + EPSV);
        uvec4 w0, w1;
        #pragma unroll
        for (int p = 0; p < 8; ++p) {
            float e[2];
            #pragma unroll
            for (int z = 0; z < 2; ++z) {
                const int j = h * 16 + p * 2 + z;
                const float nf = (float)(K - j);                // Trev[j] = exp((th+(K-j)D)^2 * nit)
                const float x  = fmaf(nf, DELTA_F, th);
                e[z] = __expf(x * x * nit);
            }
            const unsigned int pk = (unsigned int)f2bf(e[0]) |
                                    ((unsigned int)f2bf(e[1]) << 16);
            if (p < 4) w0[p] = pk; else w1[p - 4] = pk;
        }
        char* rowp = (char*)Trev + v * 96 + ((v >> 3) & 1) * 32 + h * 32;
        *(uvec4*)rowp        = w0;
        *(uvec4*)(rowp + 16) = w1;
    }

    // ---------------- Phase A2: rho gaussians * mask * feat ----------------
    if (tid < NV) {
        const int v = tid;
        const float rv = rho[site * NV + v];
        const float mv = mask[site * NV + v];
        float f[6];
        #pragma unroll
        for (int c = 0; c < 5; ++c) f[c] = feat[(site * NV + v) * 5 + c];
        f[5] = 1.0f;
        #pragma unroll
        for (int r = 0; r < 5; ++r) {
            const float mr  = mu_rho[r * 16];
            const float sr  = sigma_rho[r * 16];
            const float inv = 1.0f / (sr * sr + EPSV);
            const float d   = rv - mr;
            const float rg  = __expf(-d * d * inv) * mv;
            #pragma unroll
            for (int c = 0; c < 6; ++c) {
                const int cr = r * 8 + c;
                const int byte = cr * 256 + ((v * 2) ^ ((cr & 7) << 4));
                fa_t[byte >> 1] = f2bf(rg * f[c]);
            }
        }
        // rows r*8+{6,7} uninitialized: read only as independent MFMA A rows,
        // whose C rows are discarded (c>=6 never used by normalize)
    }
    __syncthreads();

    // ---------------- per-wave setup ----------------
    const int q = lane >> 4, t = lane & 15;

    bfrag8 afrag[3][4];
    #pragma unroll
    for (int m = 0; m < 2; ++m)
        #pragma unroll
        for (int s = 0; s < 4; ++s) {
            const int cr = m * 16 + t;
            const int byte = cr * 256 + ((s * 64 + q * 16) ^ ((cr & 7) << 4));
            afrag[m][s] = *(const bfrag8*)((const char*)fa_t + byte);
        }
    #pragma unroll
    for (int s = 0; s < 4; ++s) {
        if (t < 8) {
            const int cr = 32 + t;
            const int byte = cr * 256 + ((s * 64 + q * 16) ^ ((cr & 7) << 4));
            afrag[2][s] = *(const bfrag8*)((const char*)fa_t + byte);
        } else {
            afrag[2][s] = (bfrag8){0, 0, 0, 0, 0, 0, 0, 0};
        }
    }

    // Kv for this lane's 32 gather vertices, packed u8 in 8 u32 regs
    unsigned int Kpk[4][2];
    #pragma unroll
    for (int s = 0; s < 4; ++s) {
        Kpk[s][0] = *(const unsigned int*)&K_pack[s * 32 + q * 8];
        Kpk[s][1] = *(const unsigned int*)&K_pack[s * 32 + q * 8 + 4];
    }
    const int lbase = q * 768 + (q & 1) * 32 + 2 * t;   // 96B pitch + stagger + t

    // ---------------- rotation loop (barrier-free) ----------------
    #pragma unroll
    for (int i = 0; i < 4; ++i) {
        const int k = wq * 4 + i;
        const int c15k = 15 - k;         // wave-uniform

        facc4 acc[3];
        #pragma unroll
        for (int m = 0; m < 3; ++m) acc[m] = (facc4){0.f, 0.f, 0.f, 0.f};

        #pragma unroll
        for (int s = 0; s < 4; ++s) {
            uvec4 bu;
            #pragma unroll
            for (int jp = 0; jp < 4; ++jp) {
                const int j0 = 2 * jp, j1 = 2 * jp + 1;
                const int kv0 = (Kpk[s][j0 >> 2] >> ((j0 & 3) * 8)) & 0xff;
                const int kv1 = (Kpk[s][j1 >> 2] >> ((j1 & 3) * 8)) & 0xff;
                const int e0 = (kv0 + c15k) & 15;     // off-1
                const int e1 = (kv1 + c15k) & 15;
                const unsigned int v0 = *(const unsigned short*)
                    ((const char*)Trev + (lbase + 2 * e0) + (s * 3072 + j0 * 96 + 2));
                const unsigned int v1 = *(const unsigned short*)
                    ((const char*)Trev + (lbase + 2 * e1) + (s * 3072 + j1 * 96 + 2));
                bu[jp] = v0 | (v1 << 16);
            }
            const bfrag8 b = __builtin_bit_cast(bfrag8, bu);
            acc[0] = __builtin_amdgcn_mfma_f32_16x16x32_bf16(afrag[0][s], b, acc[0], 0, 0, 0);
            acc[1] = __builtin_amdgcn_mfma_f32_16x16x32_bf16(afrag[1][s], b, acc[1], 0, 0, 0);
            acc[2] = __builtin_amdgcn_mfma_f32_16x16x32_bf16(afrag[2][s], b, acc[2], 0, 0, 0);
        }

        // in-register normalize -> desc_all (bf16)
        const int cbase = (q & 1) * 4;
        #pragma unroll
        for (int m = 0; m < 3; ++m) {
            const float den = __shfl(acc[m][1], ((q | 1) << 4) | t, 64);
            const float rcp = __builtin_amdgcn_rcpf(den + EPSV);
            const int r = 2 * m + (q >> 1);
            if (r < 5) {
                #pragma unroll
                for (int jj = 0; jj < 4; ++jj) {
                    const int c = cbase + jj;                 // = w when < 5
                    if (c < 5) {
                        const float val = acc[m][jj] * rcp;
                        desc_all[(c * 16 + k) * 104 + r * 16 + t] = f2bf(val);
                    }
                }
            }
        }
    }
    __syncthreads();

    // ---------------- B3: cf[k][o] = desc[w] @ W[w], max over k ----------------
    for (int u = wq; u < 25; u += 4) {
        const int w  = u / 5;
        const int ot = u - w * 5;
        const int o  = ot * 16 + (lane & 15);
        facc4 acc = {0.f, 0.f, 0.f, 0.f};
        #pragma unroll
        for (int s = 0; s < 3; ++s) {
            const bfrag8 a = *(const bfrag8*)
                &desc_all[(w * 16 + (lane & 15)) * 104 + s * 32 + (lane >> 4) * 8];
            bfrag8 bf;
            if (wf) {
                bf = *(const bfrag8*)&wf[((size_t)((w * 5 + ot) * 3 + s)) * 512 + lane * 8];
            } else {
                #pragma unroll
                for (int j = 0; j < 8; ++j) {
                    const int g = s * 32 + (lane >> 4) * 8 + j;
                    const float val = (g < 80) ? Wc[(w * 80 + g) * 80 + o] : 0.0f;
                    bf[j] = (short)f2bf(val);
                }
            }
            acc = __builtin_amdgcn_mfma_f32_16x16x32_bf16(a, bf, acc, 0, 0, 0);
        }
        float mx = fmaxf(fmaxf(acc[0], acc[1]), fmaxf(acc[2], acc[3]));
        mx = fmaxf(mx, __shfl_xor(mx, 16, 64));
        mx = fmaxf(mx, __shfl_xor(mx, 32, 64));
        if (lane < 16) {
            out[(size_t)site * 400 + w * 80 + o] = mx + bc[w * 80 + o];
        }
    }
}

extern "C" void kernel_launch(void* const* d_in, const int* in_sizes, int n_in,
                              void* d_out, int out_size, void* d_ws, size_t ws_size,
                              hipStream_t stream) {
    const float* feat        = (const float*)d_in[0];
    const float* rho         = (const float*)d_in[1];
    const float* theta       = (const float*)d_in[2];
    const float* mask        = (const float*)d_in[3];
    const float* mu_rho      = (const float*)d_in[4];
    const float* mu_theta    = (const float*)d_in[5];
    const float* sigma_rho   = (const float*)d_in[6];
    const float* sigma_theta = (const float*)d_in[7];
    const float* Wc          = (const float*)d_in[8];
    const float* bc          = (const float*)d_in[9];
    float* outp              = (float*)d_out;

    unsigned short* wfp = nullptr;
    if (ws_size >= (size_t)75 * 512 * sizeof(unsigned short)) {
        wfp = (unsigned short*)d_ws;
        pack_w<<<19, 256, 0, stream>>>(Wc, wfp);
    }

    const int sites = in_sizes[1] / NV;   // B*S = 4096
    lsres_kernel<<<sites, 256, 0, stream>>>(feat, rho, theta, mask,
                                            mu_rho, mu_theta, sigma_rho, sigma_theta,
                                            Wc, bc, wfp, outp);
}